// Round 10
// baseline (446.560 us; speedup 1.0000x reference)
//
#include <hip/hip_runtime.h>
#include <math.h>

#define B 64
#define P 16800
#define O 64
#define THRESH 0.35f
#define VALID_T 0.2f
#define HB 2048            // coarse hist bins = top 11 bits of float bits (rank >= 0)
#define HSHIFT 21
#define ESPLIT 16          // row splits in kE12
#define PSEG ((P + ESPLIT - 1) / ESPLIT)   // 1050
#define CCAP 4096          // per-row global candidate capacity
#define MULT 2             // priors per thread in kD1 (registers)
#define CHB (MULT * 256)   // 512 priors per kD1 block
#define NB2 ((P + CHB - 1) / CHB)          // 33 blocks per row

__device__ __forceinline__ float smooth_l1(float x) {
    float ax = fabsf(x);
    return ax < 1.f ? 0.5f * ax * ax : ax - 0.5f;
}
__device__ __forceinline__ float lse2(float c0, float c1) {   // shared: kD1 + fixup
    float m = fmaxf(c0, c1);
    return m + __logf(__expf(c0 - m) + __expf(c1 - m));
}
__device__ __forceinline__ float wave_sum(float v) {
#pragma unroll
    for (int s = 32; s > 0; s >>= 1) v += __shfl_down(v, s, 64);
    return v;
}
__device__ __forceinline__ int wave_sum_i(int v) {
#pragma unroll
    for (int s = 32; s > 0; s >>= 1) v += __shfl_down(v, s, 64);
    return v;
}
__device__ __forceinline__ float wave_min(float v) {
#pragma unroll
    for (int s = 32; s > 0; s >>= 1) v = fminf(v, __shfl_xor(v, s, 64));
    return v;
}
__device__ __forceinline__ float wave_max(float v) {
#pragma unroll
    for (int s = 32; s > 0; s >>= 1) v = fmaxf(v, __shfl_xor(v, s, 64));
    return v;
}
// shared IoU helper: kB2z, kD1 hot path and fixup -> bit-identical recompute
__device__ __forceinline__ float iou_pt(float4 t, float area_a,
                                        float px1, float py1, float px2, float py2,
                                        float area_b) {
    float w = fmaxf(fminf(t.z, px2) - fmaxf(t.x, px1), 0.f);
    float h = fmaxf(fminf(t.w, py2) - fmaxf(t.y, py1), 0.f);
    float inter = w * h;
    return inter / (area_a + area_b - inter);
}

// ---------------- Kernel B2z: per-truth best prior via grid-pruned candidates +
// cooperative zeroing of hist/accumulator region (replaces the memset dispatch).
__global__ void __launch_bounds__(64) kB2z(
        const float* __restrict__ priors, const float* __restrict__ targets,
        unsigned long long* __restrict__ bp_final,
        int* __restrict__ zmem, int ztot) {
    for (int i = blockIdx.x * 64 + threadIdx.x; i < ztot; i += gridDim.x * 64) zmem[i] = 0;
    int o = blockIdx.x % O;
    int b = blockIdx.x / O;
    const float* tt = &targets[(b * O + o) * 15];
    float tx1 = tt[0], ty1 = tt[1], tx2 = tt[2], ty2 = tt[3];
    float area_a = (tx2 - tx1) * (ty2 - ty1);
    float4 tb = make_float4(tx1, ty1, tx2, ty2);
    unsigned long long key = (unsigned long long)0xFFFFFFFFu;   // iou=0, p=0 fallback
    const int fs[6]   = {80, 80, 40, 40, 20, 20};
    const int ms[6]   = {16, 32, 64, 128, 256, 512};
    const int base[6] = {0, 6400, 12800, 14400, 16000, 16400};
#pragma unroll
    for (int c = 0; c < 6; ++c) {
        int f = fs[c];
        float inv = (float)f;                         // 640/step == f
        float h = (float)ms[c] * (0.5f / 640.f);
        int j0 = (int)floorf((tx1 - h) * inv - 0.5f) - 1; if (j0 < 0) j0 = 0;
        int j1 = (int)ceilf((tx2 + h) * inv - 0.5f) + 1;  if (j1 > f - 1) j1 = f - 1;
        int i0 = (int)floorf((ty1 - h) * inv - 0.5f) - 1; if (i0 < 0) i0 = 0;
        int i1 = (int)ceilf((ty2 + h) * inv - 0.5f) + 1;  if (i1 > f - 1) i1 = f - 1;
        if (j1 < j0 || i1 < i0) continue;
        int nj = j1 - j0 + 1;
        int n = (i1 - i0 + 1) * nj;
        for (int idx = threadIdx.x; idx < n; idx += 64) {
            int ii = i0 + idx / nj, jj = j0 + idx % nj;
            int p = base[c] + ii * f + jj;
            float4 q = ((const float4*)priors)[p];
            float px1 = q.x - q.z * 0.5f, py1 = q.y - q.w * 0.5f;
            float px2 = q.x + q.z * 0.5f, py2 = q.y + q.w * 0.5f;
            float areab = (px2 - px1) * (py2 - py1);
            float iou = iou_pt(tb, area_a, px1, py1, px2, py2, areab);
            unsigned long long kk = ((unsigned long long)__float_as_uint(iou) << 32)
                                  | (unsigned)(0xFFFFFFFFu - (unsigned)p);
            if (kk > key) key = kk;                   // ties -> smaller p (ref argmax)
        }
    }
#pragma unroll
    for (int s = 32; s > 0; s >>= 1) {
        unsigned long long om = __shfl_xor(key, s, 64);
        if (om > key) key = om;
    }
    if (threadIdx.x == 0) bp_final[b * O + o] = key;
}

// ---------------- Kernel D1: fused kA+kD main pass; the LAST block of each row
// (row_done counter) additionally runs the scatter fixup + findbin (old kC2+kE0).
__global__ void __launch_bounds__(256) kD1_main(
        const float* __restrict__ loc_data, const float* __restrict__ conf_data,
        const float* __restrict__ landm_data, const float* __restrict__ priors,
        const float* __restrict__ targets,
        const unsigned long long* __restrict__ bp_final,
        float* __restrict__ rank, int* __restrict__ hist,
        int* __restrict__ num_pos, float* __restrict__ pos_ce,
        float* __restrict__ gsum, int* __restrict__ np1_tot, int* __restrict__ np_tot,
        int* __restrict__ row_done, int* __restrict__ binArr, int* __restrict__ kkArr) {
    int blk = blockIdx.x % NB2;
    int b = blockIdx.x / NB2;
    int p0 = blk * CHB;
    __shared__ float4 t4[O];
    __shared__ float ta[O], lab[O];
    __shared__ float lm[O][10];
    __shared__ int lhist[HB];
    __shared__ float4 wbb[4];
    __shared__ int alist[O];
    __shared__ int s_cnt, s_last, s_np;
    __shared__ int sp2[O];
    __shared__ int chunkSum[256];
    __shared__ float wredf[3][4];
    __shared__ int wredi[2][4];
    int tid = threadIdx.x;
    if (tid < O) {
        const float* t = &targets[(b * O + tid) * 15];
        float a0 = t[0], a1 = t[1], a2 = t[2], a3 = t[3];
        t4[tid] = make_float4(a0, a1, a2, a3);
        ta[tid] = (a2 - a0) * (a3 - a1);
        lab[tid] = t[14];
    }
    for (int i = tid; i < O * 10; i += 256)
        lm[i / 10][i % 10] = targets[b * O * 15 + (i / 10) * 15 + 4 + (i % 10)];
    for (int i = tid; i < HB; i += 256) lhist[i] = 0;
    // MULT priors in registers + per-wave bbox
    float px1[MULT], py1[MULT], px2[MULT], py2[MULT], areab[MULT];
    float4 pr4[MULT];
    float best[MULT]; int bi[MULT]; bool act[MULT];
    float bx1 = 1e30f, by1 = 1e30f, bx2 = -1e30f, by2 = -1e30f;
#pragma unroll
    for (int mi = 0; mi < MULT; ++mi) {
        int p = p0 + mi * 256 + tid;
        act[mi] = (p < P);
        int pc = act[mi] ? p : (P - 1);
        float4 q = ((const float4*)priors)[pc];
        pr4[mi] = q;
        px1[mi] = q.x - q.z * 0.5f; py1[mi] = q.y - q.w * 0.5f;
        px2[mi] = q.x + q.z * 0.5f; py2[mi] = q.y + q.w * 0.5f;
        areab[mi] = (px2[mi] - px1[mi]) * (py2[mi] - py1[mi]);
        bx1 = fminf(bx1, px1[mi]); by1 = fminf(by1, py1[mi]);
        bx2 = fmaxf(bx2, px2[mi]); by2 = fmaxf(by2, py2[mi]);
        best[mi] = 0.f; bi[mi] = 0;   // all-zero -> argmax 0, ov 0 (matches ref)
    }
    bx1 = wave_min(bx1); by1 = wave_min(by1);
    bx2 = wave_max(bx2); by2 = wave_max(by2);
    int wid = tid >> 6, lid = tid & 63;
    if (lid == 0) wbb[wid] = make_float4(bx1, by1, bx2, by2);
    __syncthreads();
    if (tid < 64) {
        float ux1 = fminf(fminf(wbb[0].x, wbb[1].x), fminf(wbb[2].x, wbb[3].x));
        float uy1 = fminf(fminf(wbb[0].y, wbb[1].y), fminf(wbb[2].y, wbb[3].y));
        float ux2 = fmaxf(fmaxf(wbb[0].z, wbb[1].z), fmaxf(wbb[2].z, wbb[3].z));
        float uy2 = fmaxf(fmaxf(wbb[0].w, wbb[1].w), fmaxf(wbb[2].w, wbb[3].w));
        float4 t = t4[tid];
        bool pass = (fminf(t.z, ux2) - fmaxf(t.x, ux1) > 0.f) &&
                    (fminf(t.w, uy2) - fmaxf(t.y, uy1) > 0.f);
        unsigned long long mask = __ballot(pass);
        if (tid == 0) s_cnt = __popcll(mask);
        if (pass) {
            int pos = __popcll(mask & ((1ull << tid) - 1ull));
            alist[pos] = tid;          // ballot-compaction preserves increasing o
        }
    }
    __syncthreads();
    int cnt = s_cnt;
    for (int li = 0; li < cnt; ++li) {
        int o = alist[li];
        float4 t = t4[o];
        float w0 = fminf(t.z, bx2) - fmaxf(t.x, bx1);
        float h0 = fminf(t.w, by2) - fmaxf(t.y, by1);
        if (w0 <= 0.f || h0 <= 0.f) continue;   // wave-uniform refinement
        float area_a = ta[o];
#pragma unroll
        for (int mi = 0; mi < MULT; ++mi) {
            float iou = iou_pt(t, area_a, px1[mi], py1[mi], px2[mi], py2[mi], areab[mi]);
            if (iou > best[mi]) { best[mi] = iou; bi[mi] = o; }   // strict >: first max
        }
    }
    // per-prior epilogue (no override; fixup below corrects the <=64 scattered priors)
    float ll = 0.f, llm = 0.f, cep = 0.f;
    int cp = 0, cp1 = 0;
#pragma unroll
    for (int mi = 0; mi < MULT; ++mi) {
        if (!act[mi]) continue;
        int p = p0 + mi * 256 + tid;
        int conf = (best[mi] >= THRESH) ? (int)lab[bi[mi]] : 0;   // label +-1.0 exact
        float2 c01 = ((const float2*)conf_data)[b * P + p];
        float c0 = c01.x, c1 = c01.y;
        float lse = lse2(c0, c1);
        bool pos = conf != 0;
        float ce = lse - (pos ? c1 : c0);
        float rv = pos ? 0.f : ce;
        rank[(size_t)b * P + p] = rv;
        atomicAdd(&lhist[__float_as_uint(rv) >> HSHIFT], 1);
        if (pos) {
            cp++; cep += ce;
            int ti = bi[mi];
            float cx = pr4[mi].x, cy = pr4[mi].y, sw = pr4[mi].z, sh = pr4[mi].w;
            float4 t = t4[ti];
            float gx = ((t.x + t.z) * 0.5f - cx) / (0.1f * sw);
            float gy = ((t.y + t.w) * 0.5f - cy) / (0.1f * sh);
            float gw = logf((t.z - t.x) / sw) / 0.2f;
            float gh = logf((t.w - t.y) / sh) / 0.2f;
            const float* ld = &loc_data[(size_t)(b * P + p) * 4];
            ll += smooth_l1(ld[0] - gx) + smooth_l1(ld[1] - gy) +
                  smooth_l1(ld[2] - gw) + smooth_l1(ld[3] - gh);
            if (conf > 0) {
                cp1++;
                const float* lmd = &landm_data[(size_t)(b * P + p) * 10];
                for (int k5 = 0; k5 < 5; ++k5) {
                    float lx = (lm[ti][k5 * 2 + 0] - cx) / (0.1f * sw);
                    float ly = (lm[ti][k5 * 2 + 1] - cy) / (0.1f * sh);
                    llm += smooth_l1(lmd[k5 * 2 + 0] - lx) + smooth_l1(lmd[k5 * 2 + 1] - ly);
                }
            }
        }
    }
    float s_ll = wave_sum(ll), s_llm = wave_sum(llm), s_cep = wave_sum(cep);
    int s_cp = wave_sum_i(cp), s_cp1 = wave_sum_i(cp1);
    if (lid == 0) {
        wredf[0][wid] = s_ll; wredf[1][wid] = s_llm; wredf[2][wid] = s_cep;
        wredi[0][wid] = s_cp; wredi[1][wid] = s_cp1;
    }
    __syncthreads();
    if (tid == 0) {
        float ll_t = wredf[0][0] + wredf[0][1] + wredf[0][2] + wredf[0][3];
        float llm_t = wredf[1][0] + wredf[1][1] + wredf[1][2] + wredf[1][3];
        float cep_t = wredf[2][0] + wredf[2][1] + wredf[2][2] + wredf[2][3];
        int cp_t = wredi[0][0] + wredi[0][1] + wredi[0][2] + wredi[0][3];
        int cp1_t = wredi[1][0] + wredi[1][1] + wredi[1][2] + wredi[1][3];
        if (ll_t != 0.f)  atomicAdd(&gsum[0], ll_t);
        if (llm_t != 0.f) atomicAdd(&gsum[1], llm_t);
        if (cep_t != 0.f) atomicAdd(&pos_ce[b], cep_t);
        if (cp_t)  atomicAdd(&num_pos[b], cp_t);
        if (cp1_t) atomicAdd(np1_tot, cp1_t);
    }
    int* gh = hist + (size_t)b * HB;
#pragma unroll
    for (int i = tid; i < HB; i += 256) {
        int c = lhist[i];
        if (c) atomicAdd(&gh[i], c);
    }
    // ---- row-completion protocol: last block of row b runs fixup + findbin
    __threadfence();
    if (tid == 0) s_last = (atomicAdd(&row_done[b], 1) == NB2 - 1) ? 1 : 0;
    __syncthreads();
    if (!s_last) return;
    // reload final hist row into lhist (atomics went to L2; first normal read here)
    for (int i = tid; i < HB; i += 256) lhist[i] = gh[i];
    int p = 0, v = 0;
    if (tid < O) {
        unsigned long long k = bp_final[b * O + tid];
        p = (int)(0xFFFFFFFFu - (unsigned)(k & 0xFFFFFFFFu));
        float iou = __uint_as_float((unsigned)(k >> 32));
        v = (iou >= VALID_T) ? 1 : 0;
        sp2[tid] = p;
    }
    __syncthreads();
    int dnp = 0, dn1 = 0;
    float dll = 0.f, dllm = 0.f, dce = 0.f;
    if (tid < O) {
        int j = tid;
        bool winner = true;                // last j with this p wins (numpy scatter)
        for (int jj = j + 1; jj < O; ++jj)
            if (sp2[jj] == p) { winner = false; break; }
        if (winner) {
            float4 q = ((const float4*)priors)[p];
            float qx1 = q.x - q.z * 0.5f, qy1 = q.y - q.w * 0.5f;
            float qx2 = q.x + q.z * 0.5f, qy2 = q.y + q.w * 0.5f;
            float areab = (qx2 - qx1) * (qy2 - qy1);
            float bst = 0.f; int bio = 0;
            for (int o = 0; o < O; ++o) {   // ascending o: bit-identical to hot path
                float io = iou_pt(t4[o], ta[o], qx1, qy1, qx2, qy2, areab);
                if (io > bst) { bst = io; bio = o; }
            }
            float ov_new = v ? 2.0f : bst;
            int conf_old = (bst >= THRESH) ? (int)lab[bio] : 0;
            int conf_new = (ov_new >= THRESH) ? (int)lab[j] : 0;
            float2 c01 = ((const float2*)conf_data)[b * P + p];
            float c0 = c01.x, c1 = c01.y;
            float lse = lse2(c0, c1);
            bool po = conf_old != 0, pn = conf_new != 0;
            float ceo = lse - (po ? c1 : c0), cen = lse - (pn ? c1 : c0);
            float rvo = po ? 0.f : ceo, rvn = pn ? 0.f : cen;
            if (__float_as_uint(rvo) != __float_as_uint(rvn)) {
                rank[(size_t)b * P + p] = rvn;
                int bo = __float_as_uint(rvo) >> HSHIFT, bn = __float_as_uint(rvn) >> HSHIFT;
                if (bo != bn) { atomicAdd(&lhist[bn], 1); atomicAdd(&lhist[bo], -1); }
            }
            const float* ld = &loc_data[(size_t)(b * P + p) * 4];
            auto enc_ll = [&](int ti) -> float {    // same float ops as hot epilogue
                float4 t = t4[ti];
                float gx = ((t.x + t.z) * 0.5f - q.x) / (0.1f * q.z);
                float gy = ((t.y + t.w) * 0.5f - q.y) / (0.1f * q.w);
                float gw = logf((t.z - t.x) / q.z) / 0.2f;
                float gh = logf((t.w - t.y) / q.w) / 0.2f;
                return smooth_l1(ld[0] - gx) + smooth_l1(ld[1] - gy) +
                       smooth_l1(ld[2] - gw) + smooth_l1(ld[3] - gh);
            };
            if (po) dll -= enc_ll(bio);
            if (pn) dll += enc_ll(j);
            dce = (pn ? cen : 0.f) - (po ? ceo : 0.f);
            dnp = (int)pn - (int)po;
            const float* lmd = &landm_data[(size_t)(b * P + p) * 10];
            auto enc_lm = [&](int ti) -> float {
                float sum = 0.f;
                for (int k5 = 0; k5 < 5; ++k5) {
                    float lx = (lm[ti][k5 * 2 + 0] - q.x) / (0.1f * q.z);
                    float ly = (lm[ti][k5 * 2 + 1] - q.y) / (0.1f * q.w);
                    sum += smooth_l1(lmd[k5 * 2 + 0] - lx) + smooth_l1(lmd[k5 * 2 + 1] - ly);
                }
                return sum;
            };
            if (conf_old > 0) dllm -= enc_lm(bio);
            if (conf_new > 0) dllm += enc_lm(j);
            dn1 = (int)(conf_new > 0) - (int)(conf_old > 0);
        }
    }
    if (tid < 64) {                        // wave 0 reduces the deltas
        float r_ll = wave_sum(dll), r_lm = wave_sum(dllm), r_ce = wave_sum(dce);
        int r_np = wave_sum_i(dnp), r_n1 = wave_sum_i(dn1);
        if (tid == 0) {
            if (r_ll != 0.f) atomicAdd(&gsum[0], r_ll);
            if (r_lm != 0.f) atomicAdd(&gsum[1], r_lm);
            if (r_ce != 0.f) pos_ce[b] += r_ce;        // row-private now
            int np = num_pos[b] + r_np;                // L2-fresh (first normal read)
            s_np = np;
            atomicAdd(np_tot, np);
            if (r_n1) atomicAdd(np1_tot, r_n1);
        }
    }
    __syncthreads();
    // ---- findbin: hist final in lhist
    int k = s_np * 7;
    if (k > P - 1) k = P - 1;
    int cs = 0;
#pragma unroll
    for (int i = 0; i < HB / 256; ++i) cs += lhist[tid * (HB / 256) + i];
    chunkSum[tid] = cs;
    __syncthreads();
    if (tid == 0) {
        if (k <= 0) { binArr[b] = -1; kkArr[b] = 0; return; }
        int cum = 0, bin = 0, kk = k;
        for (int c = 255; c >= 0; --c) {
            if (cum + chunkSum[c] >= k) {
                for (int i = HB / 256 - 1; i >= 0; --i) {
                    int hv = lhist[c * (HB / 256) + i];
                    if (cum + hv >= k) { bin = c * (HB / 256) + i; kk = k - cum; goto found; }
                    cum += hv;
                }
            }
            cum += chunkSum[c];
        }
    found:
        binArr[b] = bin; kkArr[b] = kk;
    }
}

// ---------------- Kernel E12: per-segment row scan; last segment block of each row
// resolves the k-th value and accumulates loss_c; the globally-last block writes out.
__global__ void __launch_bounds__(256) kE12(
        const float* __restrict__ rank, const int* __restrict__ binArr,
        const int* __restrict__ kkArr, float* __restrict__ sumgt_part,
        unsigned* __restrict__ cand, int* __restrict__ cand_cnt,
        const float* __restrict__ pos_ce, float* __restrict__ gsum,
        int* __restrict__ np_tot, int* __restrict__ np1_tot,
        float* __restrict__ lossc_tot, int* __restrict__ done,
        int* __restrict__ row_done2, float* __restrict__ out) {
    int seg = blockIdx.x % ESPLIT;
    int b = blockIdx.x / ESPLIT;
    int bin = binArr[b];
    int t = threadIdx.x;
    __shared__ unsigned buf[CCAP];        // phase 1: lc[PSEG]; phase 2: lcand[CCAP]
    __shared__ int hist2[256];
    __shared__ int lcnt, gbase, s_bin, s_kk, s_last;
    __shared__ float redf[256];
    __shared__ int redi[256];
    const float* r = rank + (size_t)b * P;
    if (bin >= 0) {
        unsigned lo_bound = ((unsigned)(bin + 1)) << HSHIFT;
        if (t == 0) lcnt = 0;
        __syncthreads();
        int pend = min((seg + 1) * PSEG, P);
        float sumgt = 0.f;
        for (int p = seg * PSEG + t; p < pend; p += 256) {
            float v = r[p];
            unsigned u = __float_as_uint(v);
            if (u >= lo_bound) sumgt += v;
            else if ((u >> HSHIFT) == (unsigned)bin) {
                int idx = atomicAdd(&lcnt, 1);
                buf[idx] = u;
            }
        }
        __syncthreads();
        if (t == 0 && lcnt > 0) gbase = atomicAdd(&cand_cnt[b], lcnt);
        int wid = t >> 6, lid = t & 63;
        float s = wave_sum(sumgt);
        if (lid == 0) redf[wid] = s;
        __syncthreads();
        int n = lcnt, g0 = (n > 0) ? gbase : 0;
        for (int i = t; i < n; i += 256) {
            int d = g0 + i;
            if (d < CCAP) cand[(size_t)b * CCAP + d] = buf[i];
        }
        if (t == 0) {
            float tot = redf[0] + redf[1] + redf[2] + redf[3];
            if (tot != 0.f) atomicAdd(&sumgt_part[b], tot);
        }
    }
    // ---- row protocol (all blocks, even bin<0 rows)
    __threadfence();
    __syncthreads();
    if (t == 0) s_last = (atomicAdd(&row_done2[b], 1) == ESPLIT - 1) ? 1 : 0;
    __syncthreads();
    if (!s_last) return;
    float topk_b = 0.f;
    if (bin >= 0) {
        int m = cand_cnt[b];
        int kk0 = kkArr[b];
        const unsigned* cd = cand + (size_t)b * CCAP;
        bool useG = (m > CCAP);          // pathological overflow: rescan row
        if (!useG)
            for (int i = t; i < m; i += 256) buf[i] = cd[i];
        __syncthreads();
        unsigned pref = ((unsigned)bin) << HSHIFT;
        unsigned resolved = 0xFFFFFFFFu << HSHIFT;
        int kk = kk0;
        const int shifts[3] = {13, 5, 0};
        const int nbins[3] = {256, 256, 32};
        for (int pass = 0; pass < 3; ++pass) {
            int sh = shifts[pass], nb = nbins[pass];
            for (int i = t; i < nb; i += 256) hist2[i] = 0;
            __syncthreads();
            if (!useG) {
                for (int i = t; i < m; i += 256) {
                    unsigned u = buf[i];
                    if ((u & resolved) == pref) atomicAdd(&hist2[(u >> sh) & (nb - 1)], 1);
                }
            } else {
                for (int p = t; p < P; p += 256) {
                    unsigned u = __float_as_uint(r[p]);
                    if ((u & resolved) == pref) atomicAdd(&hist2[(u >> sh) & (nb - 1)], 1);
                }
            }
            __syncthreads();
            if (t == 0) {
                int cum = 0, d = 0, kn = kk;
                for (int i = nb - 1; i >= 0; --i) {
                    if (cum + hist2[i] >= kk) { d = i; kn = kk - cum; break; }
                    cum += hist2[i];
                }
                s_bin = d; s_kk = kn;
            }
            __syncthreads();
            pref |= ((unsigned)s_bin) << sh;
            resolved |= (unsigned)(nb - 1) << sh;
            kk = s_kk;
            __syncthreads();
        }
        float tv = __uint_as_float(pref);    // exact k-th largest value
        float sumS = 0.f; int cntS = 0;
        if (!useG) {
            for (int i = t; i < m; i += 256) {
                float v = __uint_as_float(buf[i]);
                if (v > tv) { sumS += v; cntS++; }
            }
        } else {
            for (int p = t; p < P; p += 256) {
                unsigned u = __float_as_uint(r[p]);
                if ((u >> HSHIFT) == (unsigned)bin) {
                    float v = __uint_as_float(u);
                    if (v > tv) { sumS += v; cntS++; }
                }
            }
        }
        redf[t] = sumS; redi[t] = cntS; __syncthreads();
        for (int s = 128; s > 0; s >>= 1) {
            if (t < s) { redf[t] += redf[t + s]; redi[t] += redi[t + s]; }
            __syncthreads();
        }
        if (t == 0) topk_b = sumgt_part[b] + redf[0] + (float)(kk0 - redi[0]) * tv;
    }
    if (t == 0) {
        atomicAdd(lossc_tot, pos_ce[b] + topk_b);
        __threadfence();
        int old = atomicAdd(done, 1);
        if (old == B - 1) {              // last row finalizes (atomic reads: L2-fresh)
            float g0 = atomicAdd(&gsum[0], 0.f);
            float g1 = atomicAdd(&gsum[1], 0.f);
            float lc = atomicAdd(lossc_tot, 0.f);
            int np = atomicAdd(np_tot, 0);
            int n1 = atomicAdd(np1_tot, 0);
            float N = fmaxf((float)np, 1.f);
            float N1 = fmaxf((float)n1, 1.f);
            out[0] = g0 / N;
            out[1] = lc / N;
            out[2] = g1 / N1;
        }
    }
}

extern "C" void kernel_launch(void* const* d_in, const int* in_sizes, int n_in,
                              void* d_out, int out_size, void* d_ws, size_t ws_size,
                              hipStream_t stream) {
    const float* loc_data   = (const float*)d_in[0];
    const float* conf_data  = (const float*)d_in[1];
    const float* landm_data = (const float*)d_in[2];
    const float* priors     = (const float*)d_in[3];
    const float* targets    = (const float*)d_in[4];
    float* out = (float*)d_out;

    char* ws = (char*)d_ws;
    size_t off = 0;
    auto alloc = [&](size_t bytes) -> void* {
        void* p = ws + off;
        off += (bytes + 255) & ~(size_t)255;
        return p;
    };
    float* rank     = (float*)alloc((size_t)B * P * 4);
    unsigned long long* bp_final = (unsigned long long*)alloc((size_t)B * O * 8);
    unsigned* cand  = (unsigned*)alloc((size_t)B * CCAP * 4);
    int* binArr     = (int*)alloc(B * 4);
    int* kkArr      = (int*)alloc(B * 4);
    // zero region: hist (B*HB ints) + accumulators, contiguous (alloc keeps 256B
    // alignment and hist_bytes is a multiple of 256 so acc directly follows)
    size_t hist_bytes = (size_t)B * HB * 4;
    char* zbase = (char*)alloc(hist_bytes);
    int* hist = (int*)zbase;
    size_t acc_bytes = (size_t)(B * 6 * 4 + 64);
    char* acc = (char*)alloc(acc_bytes);
    int*   num_pos      = (int*)acc;
    float* pos_ce       = (float*)(acc + B * 4);
    int*   cand_cnt     = (int*)(acc + 2 * B * 4);
    float* sumgt_part   = (float*)(acc + 3 * B * 4);
    int*   row_done     = (int*)(acc + 4 * B * 4);
    int*   row_done2    = (int*)(acc + 5 * B * 4);
    float* gsum         = (float*)(acc + 6 * B * 4);       // 2 floats
    int*   np1_tot      = (int*)(acc + 6 * B * 4 + 8);
    int*   np_tot       = (int*)(acc + 6 * B * 4 + 12);
    float* lossc_tot    = (float*)(acc + 6 * B * 4 + 16);
    int*   done         = (int*)(acc + 6 * B * 4 + 20);
    int ztot = (int)((hist_bytes + acc_bytes) / 4);

    kB2z<<<dim3(B * O), dim3(64), 0, stream>>>(priors, targets, bp_final, (int*)zbase, ztot);
    kD1_main<<<dim3(B * NB2), dim3(256), 0, stream>>>(loc_data, conf_data, landm_data, priors,
                                                      targets, bp_final, rank, hist, num_pos,
                                                      pos_ce, gsum, np1_tot, np_tot, row_done,
                                                      binArr, kkArr);
    kE12<<<dim3(B * ESPLIT), dim3(256), 0, stream>>>(rank, binArr, kkArr, sumgt_part, cand,
                                                     cand_cnt, pos_ce, gsum, np_tot, np1_tot,
                                                     lossc_tot, done, row_done2, out);
}

// Round 11
// 235.069 us; speedup vs baseline: 1.8997x; 1.8997x over previous
//
#include <hip/hip_runtime.h>
#include <math.h>

#define B 64
#define P 16800
#define O 64
#define THRESH 0.35f
#define VALID_T 0.2f
#define HB 2048            // coarse hist bins = top 11 bits of float bits (rank >= 0)
#define HSHIFT 21
#define ESPLIT 16          // row splits in kE1
#define PSEG ((P + ESPLIT - 1) / ESPLIT)   // 1050
#define CCAP 4096          // per-row global candidate capacity
#define MULT 2             // priors per thread in kD1 (registers)
#define CHB (MULT * 256)   // 512 priors per kD1 block
#define NB2 ((P + CHB - 1) / CHB)          // 33 blocks per row

__device__ __forceinline__ float smooth_l1(float x) {
    float ax = fabsf(x);
    return ax < 1.f ? 0.5f * ax * ax : ax - 0.5f;
}
// fast LSE -- used IDENTICALLY by kD1 hot path and kC2 fixup (bit-identical deltas)
__device__ __forceinline__ float lse2(float c0, float c1) {
    float m = fmaxf(c0, c1);
    return m + __logf(__expf(c0 - m) + __expf(c1 - m));
}
__device__ __forceinline__ float wave_sum(float v) {
#pragma unroll
    for (int s = 32; s > 0; s >>= 1) v += __shfl_down(v, s, 64);
    return v;
}
__device__ __forceinline__ int wave_sum_i(int v) {
#pragma unroll
    for (int s = 32; s > 0; s >>= 1) v += __shfl_down(v, s, 64);
    return v;
}
__device__ __forceinline__ float wave_min(float v) {
#pragma unroll
    for (int s = 32; s > 0; s >>= 1) v = fminf(v, __shfl_xor(v, s, 64));
    return v;
}
__device__ __forceinline__ float wave_max(float v) {
#pragma unroll
    for (int s = 32; s > 0; s >>= 1) v = fmaxf(v, __shfl_xor(v, s, 64));
    return v;
}
// shared IoU helper: kB2z, kD1 and kC2 -> bit-identical recompute
__device__ __forceinline__ float iou_pt(float4 t, float area_a,
                                        float px1, float py1, float px2, float py2,
                                        float area_b) {
    float w = fmaxf(fminf(t.z, px2) - fmaxf(t.x, px1), 0.f);
    float h = fmaxf(fminf(t.w, py2) - fmaxf(t.y, py1), 0.f);
    float inter = w * h;
    return inter / (area_a + area_b - inter);
}

// ---------------- Kernel B2z: per-truth best prior via grid-pruned candidates +
// cooperative zeroing of hist/accumulator region (replaces the memset dispatch;
// visibility to kD1 guaranteed by the dispatch boundary -- NO fences).
__global__ void __launch_bounds__(64) kB2z(
        const float* __restrict__ priors, const float* __restrict__ targets,
        unsigned long long* __restrict__ bp_final,
        int* __restrict__ zmem, int ztot) {
    for (int i = blockIdx.x * 64 + threadIdx.x; i < ztot; i += gridDim.x * 64) zmem[i] = 0;
    int o = blockIdx.x % O;
    int b = blockIdx.x / O;
    const float* tt = &targets[(b * O + o) * 15];
    float tx1 = tt[0], ty1 = tt[1], tx2 = tt[2], ty2 = tt[3];
    float area_a = (tx2 - tx1) * (ty2 - ty1);
    float4 tb = make_float4(tx1, ty1, tx2, ty2);
    unsigned long long key = (unsigned long long)0xFFFFFFFFu;   // iou=0, p=0 fallback
    const int fs[6]   = {80, 80, 40, 40, 20, 20};
    const int ms[6]   = {16, 32, 64, 128, 256, 512};
    const int base[6] = {0, 6400, 12800, 14400, 16000, 16400};
#pragma unroll
    for (int c = 0; c < 6; ++c) {
        int f = fs[c];
        float inv = (float)f;                         // 640/step == f
        float h = (float)ms[c] * (0.5f / 640.f);
        int j0 = (int)floorf((tx1 - h) * inv - 0.5f) - 1; if (j0 < 0) j0 = 0;
        int j1 = (int)ceilf((tx2 + h) * inv - 0.5f) + 1;  if (j1 > f - 1) j1 = f - 1;
        int i0 = (int)floorf((ty1 - h) * inv - 0.5f) - 1; if (i0 < 0) i0 = 0;
        int i1 = (int)ceilf((ty2 + h) * inv - 0.5f) + 1;  if (i1 > f - 1) i1 = f - 1;
        if (j1 < j0 || i1 < i0) continue;
        int nj = j1 - j0 + 1;
        int n = (i1 - i0 + 1) * nj;
        for (int idx = threadIdx.x; idx < n; idx += 64) {
            int ii = i0 + idx / nj, jj = j0 + idx % nj;
            int p = base[c] + ii * f + jj;
            float4 q = ((const float4*)priors)[p];
            float px1 = q.x - q.z * 0.5f, py1 = q.y - q.w * 0.5f;
            float px2 = q.x + q.z * 0.5f, py2 = q.y + q.w * 0.5f;
            float areab = (px2 - px1) * (py2 - py1);
            float iou = iou_pt(tb, area_a, px1, py1, px2, py2, areab);
            unsigned long long kk = ((unsigned long long)__float_as_uint(iou) << 32)
                                  | (unsigned)(0xFFFFFFFFu - (unsigned)p);
            if (kk > key) key = kk;                   // ties -> smaller p (ref argmax)
        }
    }
#pragma unroll
    for (int s = 32; s > 0; s >>= 1) {
        unsigned long long om = __shfl_xor(key, s, 64);
        if (om > key) key = om;
    }
    if (threadIdx.x == 0) bp_final[b * O + o] = key;
}

// ---------------- Kernel D1 (fused kA+kD, no-override epilogue, active-truth list):
// block bbox prunes the truth set ONCE per block; waves iterate only listed truths.
__global__ void __launch_bounds__(256) kD1_main(
        const float* __restrict__ loc_data, const float* __restrict__ conf_data,
        const float* __restrict__ landm_data, const float* __restrict__ priors,
        const float* __restrict__ targets,
        float* __restrict__ rank, int* __restrict__ hist,
        int* __restrict__ num_pos, float* __restrict__ pos_ce,
        float* __restrict__ gsum, int* __restrict__ np1_tot) {
    int blk = blockIdx.x % NB2;
    int b = blockIdx.x / NB2;
    int p0 = blk * CHB;
    __shared__ float4 t4[O];
    __shared__ float ta[O], lab[O];
    __shared__ float lm[O][10];
    __shared__ int lhist[HB];
    __shared__ float4 wbb[4];
    __shared__ int alist[O];
    __shared__ int s_cnt;
    __shared__ float wredf[3][4];
    __shared__ int wredi[2][4];
    int tid = threadIdx.x;
    if (tid < O) {
        const float* t = &targets[(b * O + tid) * 15];
        float a0 = t[0], a1 = t[1], a2 = t[2], a3 = t[3];
        t4[tid] = make_float4(a0, a1, a2, a3);
        ta[tid] = (a2 - a0) * (a3 - a1);
        lab[tid] = t[14];
    }
    for (int i = tid; i < O * 10; i += 256)
        lm[i / 10][i % 10] = targets[b * O * 15 + (i / 10) * 15 + 4 + (i % 10)];
    for (int i = tid; i < HB; i += 256) lhist[i] = 0;
    // MULT priors in registers + per-wave bbox
    float px1[MULT], py1[MULT], px2[MULT], py2[MULT], areab[MULT];
    float4 pr4[MULT];
    float best[MULT]; int bi[MULT]; bool act[MULT];
    float bx1 = 1e30f, by1 = 1e30f, bx2 = -1e30f, by2 = -1e30f;
#pragma unroll
    for (int mi = 0; mi < MULT; ++mi) {
        int p = p0 + mi * 256 + tid;
        act[mi] = (p < P);
        int pc = act[mi] ? p : (P - 1);
        float4 q = ((const float4*)priors)[pc];
        pr4[mi] = q;
        px1[mi] = q.x - q.z * 0.5f; py1[mi] = q.y - q.w * 0.5f;
        px2[mi] = q.x + q.z * 0.5f; py2[mi] = q.y + q.w * 0.5f;
        areab[mi] = (px2[mi] - px1[mi]) * (py2[mi] - py1[mi]);
        bx1 = fminf(bx1, px1[mi]); by1 = fminf(by1, py1[mi]);
        bx2 = fmaxf(bx2, px2[mi]); by2 = fmaxf(by2, py2[mi]);
        best[mi] = 0.f; bi[mi] = 0;   // all-zero -> argmax 0, ov 0 (matches ref)
    }
    bx1 = wave_min(bx1); by1 = wave_min(by1);
    bx2 = wave_max(bx2); by2 = wave_max(by2);
    int wid = tid >> 6, lid = tid & 63;
    if (lid == 0) wbb[wid] = make_float4(bx1, by1, bx2, by2);
    __syncthreads();
    if (tid < 64) {
        float ux1 = fminf(fminf(wbb[0].x, wbb[1].x), fminf(wbb[2].x, wbb[3].x));
        float uy1 = fminf(fminf(wbb[0].y, wbb[1].y), fminf(wbb[2].y, wbb[3].y));
        float ux2 = fmaxf(fmaxf(wbb[0].z, wbb[1].z), fmaxf(wbb[2].z, wbb[3].z));
        float uy2 = fmaxf(fmaxf(wbb[0].w, wbb[1].w), fmaxf(wbb[2].w, wbb[3].w));
        float4 t = t4[tid];
        bool pass = (fminf(t.z, ux2) - fmaxf(t.x, ux1) > 0.f) &&
                    (fminf(t.w, uy2) - fmaxf(t.y, uy1) > 0.f);
        unsigned long long mask = __ballot(pass);
        if (tid == 0) s_cnt = __popcll(mask);
        if (pass) {
            int pos = __popcll(mask & ((1ull << tid) - 1ull));
            alist[pos] = tid;          // ballot-compaction preserves increasing o
        }
    }
    __syncthreads();
    int cnt = s_cnt;
    for (int li = 0; li < cnt; ++li) {
        int o = alist[li];
        float4 t = t4[o];
        float w0 = fminf(t.z, bx2) - fmaxf(t.x, bx1);
        float h0 = fminf(t.w, by2) - fmaxf(t.y, by1);
        if (w0 <= 0.f || h0 <= 0.f) continue;   // wave-uniform refinement
        float area_a = ta[o];
#pragma unroll
        for (int mi = 0; mi < MULT; ++mi) {
            float iou = iou_pt(t, area_a, px1[mi], py1[mi], px2[mi], py2[mi], areab[mi]);
            if (iou > best[mi]) { best[mi] = iou; bi[mi] = o; }   // strict >: first max
        }
    }
    // per-prior epilogue (no override; kC2 fixes the <=64 scattered priors later)
    float ll = 0.f, llm = 0.f, cep = 0.f;
    int cp = 0, cp1 = 0;
#pragma unroll
    for (int mi = 0; mi < MULT; ++mi) {
        if (!act[mi]) continue;
        int p = p0 + mi * 256 + tid;
        int conf = (best[mi] >= THRESH) ? (int)lab[bi[mi]] : 0;   // label +-1.0 exact
        float2 c01 = ((const float2*)conf_data)[b * P + p];
        float c0 = c01.x, c1 = c01.y;
        float lse = lse2(c0, c1);
        bool pos = conf != 0;
        float ce = lse - (pos ? c1 : c0);
        float rv = pos ? 0.f : ce;
        rank[(size_t)b * P + p] = rv;
        atomicAdd(&lhist[__float_as_uint(rv) >> HSHIFT], 1);
        if (pos) {
            cp++; cep += ce;
            int ti = bi[mi];
            float cx = pr4[mi].x, cy = pr4[mi].y, sw = pr4[mi].z, sh = pr4[mi].w;
            float4 t = t4[ti];
            float gx = ((t.x + t.z) * 0.5f - cx) / (0.1f * sw);
            float gy = ((t.y + t.w) * 0.5f - cy) / (0.1f * sh);
            float gw = logf((t.z - t.x) / sw) / 0.2f;
            float gh = logf((t.w - t.y) / sh) / 0.2f;
            const float* ld = &loc_data[(size_t)(b * P + p) * 4];
            ll += smooth_l1(ld[0] - gx) + smooth_l1(ld[1] - gy) +
                  smooth_l1(ld[2] - gw) + smooth_l1(ld[3] - gh);
            if (conf > 0) {
                cp1++;
                const float* lmd = &landm_data[(size_t)(b * P + p) * 10];
                for (int k5 = 0; k5 < 5; ++k5) {
                    float lx = (lm[ti][k5 * 2 + 0] - cx) / (0.1f * sw);
                    float ly = (lm[ti][k5 * 2 + 1] - cy) / (0.1f * sh);
                    llm += smooth_l1(lmd[k5 * 2 + 0] - lx) + smooth_l1(lmd[k5 * 2 + 1] - ly);
                }
            }
        }
    }
    float s_ll = wave_sum(ll), s_llm = wave_sum(llm), s_cep = wave_sum(cep);
    int s_cp = wave_sum_i(cp), s_cp1 = wave_sum_i(cp1);
    if (lid == 0) {
        wredf[0][wid] = s_ll; wredf[1][wid] = s_llm; wredf[2][wid] = s_cep;
        wredi[0][wid] = s_cp; wredi[1][wid] = s_cp1;
    }
    __syncthreads();
    if (tid == 0) {
        float ll_t = wredf[0][0] + wredf[0][1] + wredf[0][2] + wredf[0][3];
        float llm_t = wredf[1][0] + wredf[1][1] + wredf[1][2] + wredf[1][3];
        float cep_t = wredf[2][0] + wredf[2][1] + wredf[2][2] + wredf[2][3];
        int cp_t = wredi[0][0] + wredi[0][1] + wredi[0][2] + wredi[0][3];
        int cp1_t = wredi[1][0] + wredi[1][1] + wredi[1][2] + wredi[1][3];
        if (ll_t != 0.f)  atomicAdd(&gsum[0], ll_t);
        if (llm_t != 0.f) atomicAdd(&gsum[1], llm_t);
        if (cep_t != 0.f) atomicAdd(&pos_ce[b], cep_t);
        if (cp_t)  atomicAdd(&num_pos[b], cp_t);
        if (cp1_t) atomicAdd(np1_tot, cp1_t);
    }
    int* gh = hist + (size_t)b * HB;
#pragma unroll
    for (int i = tid; i < HB; i += 256) {
        int c = lhist[i];
        if (c) atomicAdd(&gh[i], c);
    }
}

// ---------------- Kernel C2 (fixup + findbin): dedup scatter (last j wins), recompute
// the <=64 overridden priors exactly, apply deltas; hist fixed in an LDS copy and the
// coarse bin selected here (kE0 merged). Row state is block-private after kD1.
__global__ void __launch_bounds__(256) kC2_fixup(
        const float* __restrict__ priors, const float* __restrict__ targets,
        const float* __restrict__ loc_data, const float* __restrict__ conf_data,
        const float* __restrict__ landm_data,
        const unsigned long long* __restrict__ bp_final,
        float* __restrict__ rank, const int* __restrict__ hist,
        int* __restrict__ num_pos, float* __restrict__ pos_ce,
        float* __restrict__ gsum, int* __restrict__ np1_tot, int* __restrict__ np_tot,
        int* __restrict__ binArr, int* __restrict__ kkArr) {
    int b = blockIdx.x;
    int tid = threadIdx.x;
    __shared__ float4 t4[O];
    __shared__ float ta[O], lab[O];
    __shared__ int sp[O];
    __shared__ int lh[HB];
    __shared__ int chunkSum[256];
    __shared__ int s_np;
    for (int i = tid; i < HB; i += 256) lh[i] = hist[(size_t)b * HB + i];
    int p = 0, v = 0;
    if (tid < O) {
        const float* tt = &targets[(b * O + tid) * 15];
        float4 tj = make_float4(tt[0], tt[1], tt[2], tt[3]);
        t4[tid] = tj;
        ta[tid] = (tj.z - tj.x) * (tj.w - tj.y);
        lab[tid] = tt[14];
        unsigned long long k = bp_final[b * O + tid];
        p = (int)(0xFFFFFFFFu - (unsigned)(k & 0xFFFFFFFFu));
        float iou = __uint_as_float((unsigned)(k >> 32));
        v = (iou >= VALID_T) ? 1 : 0;
        sp[tid] = p;
    }
    __syncthreads();
    int dnp = 0, dn1 = 0;
    float dll = 0.f, dllm = 0.f, dce = 0.f;
    if (tid < O) {
        int j = tid;
        bool winner = true;                // last j with this p wins (numpy scatter)
        for (int jj = j + 1; jj < O; ++jj)
            if (sp[jj] == p) { winner = false; break; }
        if (winner) {
            float4 q = ((const float4*)priors)[p];
            float px1 = q.x - q.z * 0.5f, py1 = q.y - q.w * 0.5f;
            float px2 = q.x + q.z * 0.5f, py2 = q.y + q.w * 0.5f;
            float areab = (px2 - px1) * (py2 - py1);
            float best = 0.f; int bi = 0;
            for (int o = 0; o < O; ++o) {   // ascending o: bit-identical to hot path
                float io = iou_pt(t4[o], ta[o], px1, py1, px2, py2, areab);
                if (io > best) { best = io; bi = o; }
            }
            float ov_new = v ? 2.0f : best;
            int conf_old = (best >= THRESH) ? (int)lab[bi] : 0;
            int conf_new = (ov_new >= THRESH) ? (int)lab[j] : 0;
            float2 c01 = ((const float2*)conf_data)[b * P + p];
            float c0 = c01.x, c1 = c01.y;
            float lse = lse2(c0, c1);
            bool po = conf_old != 0, pn = conf_new != 0;
            float ceo = lse - (po ? c1 : c0), cen = lse - (pn ? c1 : c0);
            float rvo = po ? 0.f : ceo, rvn = pn ? 0.f : cen;
            if (__float_as_uint(rvo) != __float_as_uint(rvn)) {
                rank[(size_t)b * P + p] = rvn;
                int bo = __float_as_uint(rvo) >> HSHIFT, bn = __float_as_uint(rvn) >> HSHIFT;
                if (bo != bn) { atomicAdd(&lh[bn], 1); atomicAdd(&lh[bo], -1); }
            }
            const float* ld = &loc_data[(size_t)(b * P + p) * 4];
            auto enc_ll = [&](int ti) -> float {    // same float ops as kD1 epilogue
                float4 t = t4[ti];
                float gx = ((t.x + t.z) * 0.5f - q.x) / (0.1f * q.z);
                float gy = ((t.y + t.w) * 0.5f - q.y) / (0.1f * q.w);
                float gw = logf((t.z - t.x) / q.z) / 0.2f;
                float gh = logf((t.w - t.y) / q.w) / 0.2f;
                return smooth_l1(ld[0] - gx) + smooth_l1(ld[1] - gy) +
                       smooth_l1(ld[2] - gw) + smooth_l1(ld[3] - gh);
            };
            if (po) dll -= enc_ll(bi);
            if (pn) dll += enc_ll(j);
            dce = (pn ? cen : 0.f) - (po ? ceo : 0.f);
            dnp = (int)pn - (int)po;
            const float* lmd = &landm_data[(size_t)(b * P + p) * 10];
            auto enc_lm = [&](int ti) -> float {
                const float* lmt = &targets[(b * O + ti) * 15 + 4];
                float sum = 0.f;
                for (int k5 = 0; k5 < 5; ++k5) {
                    float lx = (lmt[k5 * 2 + 0] - q.x) / (0.1f * q.z);
                    float ly = (lmt[k5 * 2 + 1] - q.y) / (0.1f * q.w);
                    sum += smooth_l1(lmd[k5 * 2 + 0] - lx) + smooth_l1(lmd[k5 * 2 + 1] - ly);
                }
                return sum;
            };
            if (conf_old > 0) dllm -= enc_lm(bi);
            if (conf_new > 0) dllm += enc_lm(j);
            dn1 = (int)(conf_new > 0) - (int)(conf_old > 0);
        }
    }
    if (tid < 64) {                        // wave 0 reduces the deltas
        float r_ll = wave_sum(dll), r_lm = wave_sum(dllm), r_ce = wave_sum(dce);
        int r_np = wave_sum_i(dnp), r_n1 = wave_sum_i(dn1);
        if (tid == 0) {
            if (r_ll != 0.f) atomicAdd(&gsum[0], r_ll);
            if (r_lm != 0.f) atomicAdd(&gsum[1], r_lm);
            if (r_ce != 0.f) pos_ce[b] += r_ce;        // row-private now
            int np = num_pos[b] + r_np;
            num_pos[b] = np;
            s_np = np;
            atomicAdd(np_tot, np);
            if (r_n1) atomicAdd(np1_tot, r_n1);
        }
    }
    __syncthreads();
    // ---- findbin (kE0 merged): hist is final in lh
    int k = s_np * 7;
    if (k > P - 1) k = P - 1;
    int cs = 0;
#pragma unroll
    for (int i = 0; i < HB / 256; ++i) cs += lh[tid * (HB / 256) + i];
    chunkSum[tid] = cs;
    __syncthreads();
    if (tid == 0) {
        if (k <= 0) { binArr[b] = -1; kkArr[b] = 0; return; }
        int cum = 0, bin = 0, kk = k;
        for (int c = 255; c >= 0; --c) {
            if (cum + chunkSum[c] >= k) {
                for (int i = HB / 256 - 1; i >= 0; --i) {
                    int hv = lh[c * (HB / 256) + i];
                    if (cum + hv >= k) { bin = c * (HB / 256) + i; kk = k - cum; goto found; }
                    cum += hv;
                }
            }
            cum += chunkSum[c];
        }
    found:
        binArr[b] = bin; kkArr[b] = kk;
    }
}

// ---------------- Kernel E1: parallel row scan — partial above-bin sum + candidate gather.
__global__ void kE1_scan(const float* __restrict__ rank, const int* __restrict__ binArr,
                         float* __restrict__ sumgt_part, unsigned* __restrict__ cand,
                         int* __restrict__ cand_cnt) {
    int seg = blockIdx.x % ESPLIT;
    int b = blockIdx.x / ESPLIT;
    int bin = binArr[b];
    if (bin < 0) return;
    const float* r = rank + (size_t)b * P;
    unsigned lo_bound = ((unsigned)(bin + 1)) << HSHIFT;
    __shared__ unsigned lc[PSEG];
    __shared__ int lcnt, gbase;
    __shared__ float wred[4];
    int t = threadIdx.x;
    if (t == 0) lcnt = 0;
    __syncthreads();
    int pend = min((seg + 1) * PSEG, P);
    float sumgt = 0.f;
    for (int p = seg * PSEG + t; p < pend; p += 256) {
        float v = r[p];
        unsigned u = __float_as_uint(v);
        if (u >= lo_bound) sumgt += v;
        else if ((u >> HSHIFT) == (unsigned)bin) {
            int idx = atomicAdd(&lcnt, 1);
            lc[idx] = u;
        }
    }
    __syncthreads();
    if (t == 0 && lcnt > 0) gbase = atomicAdd(&cand_cnt[b], lcnt);
    int wid = t >> 6, lid = t & 63;
    float s = wave_sum(sumgt);
    if (lid == 0) wred[wid] = s;
    __syncthreads();
    int n = lcnt, g0 = (n > 0) ? gbase : 0;
    for (int i = t; i < n; i += 256) {
        int d = g0 + i;
        if (d < CCAP) cand[(size_t)b * CCAP + d] = lc[i];
    }
    if (t == 0) {
        float tot = wred[0] + wred[1] + wred[2] + wred[3];
        if (tot != 0.f) atomicAdd(&sumgt_part[b], tot);
    }
}

// ---------------- Kernel E2: resolve remaining bits + final sum; LAST block writes out.
__global__ void kE2_resolve(const float* __restrict__ rank, const unsigned* __restrict__ cand,
                            const int* __restrict__ cand_cnt, const int* __restrict__ binArr,
                            const int* __restrict__ kkArr, const float* __restrict__ sumgt_part,
                            const float* __restrict__ pos_ce, float* __restrict__ gsum,
                            int* __restrict__ np_tot, int* __restrict__ np1_tot,
                            float* __restrict__ lossc_tot, int* __restrict__ done,
                            float* __restrict__ out) {
    int b = blockIdx.x;
    int bin = binArr[b];
    int t = threadIdx.x;
    __shared__ unsigned lcand[CCAP];
    __shared__ int hist2[256];
    __shared__ int s_bin, s_kk;
    __shared__ float redf[256];
    __shared__ int redi[256];
    float topk_b = 0.f;
    if (bin >= 0) {                      // block-uniform branch: __syncthreads safe
        int m = cand_cnt[b];
        int kk0 = kkArr[b];
        const unsigned* cd = cand + (size_t)b * CCAP;
        const float* r = rank + (size_t)b * P;
        bool useG = (m > CCAP);          // pathological overflow: rescan row
        if (!useG)
            for (int i = t; i < m; i += 256) lcand[i] = cd[i];
        __syncthreads();
        unsigned pref = ((unsigned)bin) << HSHIFT;
        unsigned resolved = 0xFFFFFFFFu << HSHIFT;
        int kk = kk0;
        const int shifts[3] = {13, 5, 0};
        const int nbins[3] = {256, 256, 32};
        for (int pass = 0; pass < 3; ++pass) {
            int sh = shifts[pass], nb = nbins[pass];
            for (int i = t; i < nb; i += 256) hist2[i] = 0;
            __syncthreads();
            if (!useG) {
                for (int i = t; i < m; i += 256) {
                    unsigned u = lcand[i];
                    if ((u & resolved) == pref) atomicAdd(&hist2[(u >> sh) & (nb - 1)], 1);
                }
            } else {
                for (int p = t; p < P; p += 256) {
                    unsigned u = __float_as_uint(r[p]);
                    if ((u & resolved) == pref) atomicAdd(&hist2[(u >> sh) & (nb - 1)], 1);
                }
            }
            __syncthreads();
            if (t == 0) {
                int cum = 0, d = 0, kn = kk;
                for (int i = nb - 1; i >= 0; --i) {
                    if (cum + hist2[i] >= kk) { d = i; kn = kk - cum; break; }
                    cum += hist2[i];
                }
                s_bin = d; s_kk = kn;
            }
            __syncthreads();
            pref |= ((unsigned)s_bin) << sh;
            resolved |= (unsigned)(nb - 1) << sh;
            kk = s_kk;
            __syncthreads();
        }
        float tv = __uint_as_float(pref);    // exact k-th largest value
        float sumS = 0.f; int cntS = 0;
        if (!useG) {
            for (int i = t; i < m; i += 256) {
                float v = __uint_as_float(lcand[i]);
                if (v > tv) { sumS += v; cntS++; }
            }
        } else {
            for (int p = t; p < P; p += 256) {
                unsigned u = __float_as_uint(r[p]);
                if ((u >> HSHIFT) == (unsigned)bin) {
                    float v = __uint_as_float(u);
                    if (v > tv) { sumS += v; cntS++; }
                }
            }
        }
        redf[t] = sumS; redi[t] = cntS; __syncthreads();
        for (int s = 128; s > 0; s >>= 1) {
            if (t < s) { redf[t] += redf[t + s]; redi[t] += redi[t + s]; }
            __syncthreads();
        }
        if (t == 0) topk_b = sumgt_part[b] + redf[0] + (float)(kk0 - redi[0]) * tv;
    }
    if (t == 0) {
        atomicAdd(lossc_tot, pos_ce[b] + topk_b);
        __threadfence();
        int old = atomicAdd(done, 1);
        if (old == B - 1) {              // last block finalizes (atomic reads: L2-fresh)
            float g0 = atomicAdd(&gsum[0], 0.f);
            float g1 = atomicAdd(&gsum[1], 0.f);
            float lc = atomicAdd(lossc_tot, 0.f);
            int np = atomicAdd(np_tot, 0);
            int n1 = atomicAdd(np1_tot, 0);
            float N = fmaxf((float)np, 1.f);
            float N1 = fmaxf((float)n1, 1.f);
            out[0] = g0 / N;
            out[1] = lc / N;
            out[2] = g1 / N1;
        }
    }
}

extern "C" void kernel_launch(void* const* d_in, const int* in_sizes, int n_in,
                              void* d_out, int out_size, void* d_ws, size_t ws_size,
                              hipStream_t stream) {
    const float* loc_data   = (const float*)d_in[0];
    const float* conf_data  = (const float*)d_in[1];
    const float* landm_data = (const float*)d_in[2];
    const float* priors     = (const float*)d_in[3];
    const float* targets    = (const float*)d_in[4];
    float* out = (float*)d_out;

    char* ws = (char*)d_ws;
    size_t off = 0;
    auto alloc = [&](size_t bytes) -> void* {
        void* p = ws + off;
        off += (bytes + 255) & ~(size_t)255;
        return p;
    };
    float* rank     = (float*)alloc((size_t)B * P * 4);
    unsigned long long* bp_final = (unsigned long long*)alloc((size_t)B * O * 8);
    unsigned* cand  = (unsigned*)alloc((size_t)B * CCAP * 4);
    int* binArr     = (int*)alloc(B * 4);
    int* kkArr      = (int*)alloc(B * 4);
    // zero region: hist (B*HB ints) + accumulators, contiguous (alloc keeps 256B
    // alignment and hist_bytes is a multiple of 256 so acc directly follows)
    size_t hist_bytes = (size_t)B * HB * 4;
    char* zbase = (char*)alloc(hist_bytes);
    int* hist = (int*)zbase;
    size_t acc_bytes = (size_t)(B * 4 * 4 + 64);
    char* acc = (char*)alloc(acc_bytes);
    int*   num_pos      = (int*)acc;
    float* pos_ce       = (float*)(acc + B * 4);
    int*   cand_cnt     = (int*)(acc + 2 * B * 4);
    float* sumgt_part   = (float*)(acc + 3 * B * 4);
    float* gsum         = (float*)(acc + 4 * B * 4);       // 2 floats
    int*   np1_tot      = (int*)(acc + 4 * B * 4 + 8);
    int*   np_tot       = (int*)(acc + 4 * B * 4 + 12);
    float* lossc_tot    = (float*)(acc + 4 * B * 4 + 16);
    int*   done         = (int*)(acc + 4 * B * 4 + 20);
    int ztot = (int)((hist_bytes + acc_bytes) / 4);

    kB2z<<<dim3(B * O), dim3(64), 0, stream>>>(priors, targets, bp_final, (int*)zbase, ztot);
    kD1_main<<<dim3(B * NB2), dim3(256), 0, stream>>>(loc_data, conf_data, landm_data, priors,
                                                      targets, rank, hist, num_pos, pos_ce,
                                                      gsum, np1_tot);
    kC2_fixup<<<dim3(B), dim3(256), 0, stream>>>(priors, targets, loc_data, conf_data,
                                                 landm_data, bp_final, rank, hist, num_pos,
                                                 pos_ce, gsum, np1_tot, np_tot, binArr, kkArr);
    kE1_scan<<<dim3(B * ESPLIT), dim3(256), 0, stream>>>(rank, binArr, sumgt_part, cand, cand_cnt);
    kE2_resolve<<<dim3(B), dim3(256), 0, stream>>>(rank, cand, cand_cnt, binArr, kkArr,
                                                   sumgt_part, pos_ce, gsum, np_tot, np1_tot,
                                                   lossc_tot, done, out);
}

// Round 12
// 222.063 us; speedup vs baseline: 2.0110x; 1.0586x over previous
//
#include <hip/hip_runtime.h>
#include <math.h>

#define B 64
#define P 16800
#define O 64
#define THRESH 0.35f
#define VALID_T 0.2f
#define HB 2048            // coarse hist bins = top 11 bits of float bits (rank >= 0)
#define HSHIFT 21
#define ESPLIT 16          // row splits in kE1
#define PSEG ((P + ESPLIT - 1) / ESPLIT)   // 1050
#define CCAP 4096          // per-row global candidate capacity
#define MULT 2             // priors per thread in kD1 (registers)
#define CHB (MULT * 256)   // 512 priors per kD1 block
#define NB2 ((P + CHB - 1) / CHB)          // 33 blocks per row

__device__ __forceinline__ float smooth_l1(float x) {
    float ax = fabsf(x);
    return ax < 1.f ? 0.5f * ax * ax : ax - 0.5f;
}
// fast LSE -- used IDENTICALLY by kD1 hot path and kC2 fixup (bit-identical deltas)
__device__ __forceinline__ float lse2(float c0, float c1) {
    float m = fmaxf(c0, c1);
    return m + __logf(__expf(c0 - m) + __expf(c1 - m));
}
// deferred-division IoU argmax update -- shared by kD1 hot path and kC2 fixup so the
// fixup's recompute is bit-identical. inter/den > bnum/bden  <=>  inter*bden > bnum*den
// (den > 0 always). One division happens only at the end (iou = bnum/bden).
__device__ __forceinline__ void iou_upd(float4 t, float area_a,
                                        float px1, float py1, float px2, float py2,
                                        float area_b,
                                        float& bnum, float& bden, int& bio, int o) {
    float w = fmaxf(fminf(t.z, px2) - fmaxf(t.x, px1), 0.f);
    float h = fmaxf(fminf(t.w, py2) - fmaxf(t.y, py1), 0.f);
    float inter = w * h;
    float den = area_a + area_b - inter;
    if (inter * bden > bnum * den) { bnum = inter; bden = den; bio = o; }
}
__device__ __forceinline__ float wave_sum(float v) {
#pragma unroll
    for (int s = 32; s > 0; s >>= 1) v += __shfl_down(v, s, 64);
    return v;
}
__device__ __forceinline__ int wave_sum_i(int v) {
#pragma unroll
    for (int s = 32; s > 0; s >>= 1) v += __shfl_down(v, s, 64);
    return v;
}
__device__ __forceinline__ float wave_min(float v) {
#pragma unroll
    for (int s = 32; s > 0; s >>= 1) v = fminf(v, __shfl_xor(v, s, 64));
    return v;
}
__device__ __forceinline__ float wave_max(float v) {
#pragma unroll
    for (int s = 32; s > 0; s >>= 1) v = fmaxf(v, __shfl_xor(v, s, 64));
    return v;
}

// ---------------- Kernel B2z: per-truth best prior via grid-pruned candidates +
// cooperative zeroing of hist/accumulator region. Rational (num,den) compare in the
// lane loop and the reduction; ONE division at the end. Ties -> smaller p (ref argmax).
__global__ void __launch_bounds__(64) kB2z(
        const float* __restrict__ priors, const float* __restrict__ targets,
        unsigned long long* __restrict__ bp_final,
        int* __restrict__ zmem, int ztot) {
    for (int i = blockIdx.x * 64 + threadIdx.x; i < ztot; i += gridDim.x * 64) zmem[i] = 0;
    int o = blockIdx.x % O;
    int b = blockIdx.x / O;
    const float* tt = &targets[(b * O + o) * 15];
    float tx1 = tt[0], ty1 = tt[1], tx2 = tt[2], ty2 = tt[3];
    float area_a = (tx2 - tx1) * (ty2 - ty1);
    float4 tb = make_float4(tx1, ty1, tx2, ty2);
    float bn = 0.f, bd = 1.f;            // iou = 0 fallback
    unsigned bp = 0u;                    // p = 0 fallback (ref argmax-of-zeros)
    const int fs[6]   = {80, 80, 40, 40, 20, 20};
    const int ms[6]   = {16, 32, 64, 128, 256, 512};
    const int base[6] = {0, 6400, 12800, 14400, 16000, 16400};
#pragma unroll
    for (int c = 0; c < 6; ++c) {
        int f = fs[c];
        float inv = (float)f;                         // 640/step == f
        float h = (float)ms[c] * (0.5f / 640.f);
        int j0 = (int)floorf((tx1 - h) * inv - 0.5f) - 1; if (j0 < 0) j0 = 0;
        int j1 = (int)ceilf((tx2 + h) * inv - 0.5f) + 1;  if (j1 > f - 1) j1 = f - 1;
        int i0 = (int)floorf((ty1 - h) * inv - 0.5f) - 1; if (i0 < 0) i0 = 0;
        int i1 = (int)ceilf((ty2 + h) * inv - 0.5f) + 1;  if (i1 > f - 1) i1 = f - 1;
        if (j1 < j0 || i1 < i0) continue;
        int nj = j1 - j0 + 1;
        int n = (i1 - i0 + 1) * nj;
        float rcp_nj = 1.0f / (float)nj;
        for (int idx = threadIdx.x; idx < n; idx += 64) {
            int ii = (int)((float)idx * rcp_nj);      // float-rcp div (guarded below)
            int jj = idx - ii * nj;
            if (jj < 0) { ii--; jj += nj; } else if (jj >= nj) { ii++; jj -= nj; }
            int p = base[c] + (i0 + ii) * f + (j0 + jj);
            float4 q = ((const float4*)priors)[p];
            float px1 = q.x - q.z * 0.5f, py1 = q.y - q.w * 0.5f;
            float px2 = q.x + q.z * 0.5f, py2 = q.y + q.w * 0.5f;
            float areab = (px2 - px1) * (py2 - py1);
            float w = fmaxf(fminf(tb.z, px2) - fmaxf(tb.x, px1), 0.f);
            float hh = fmaxf(fminf(tb.w, py2) - fmaxf(tb.y, py1), 0.f);
            float inter = w * hh;
            float den = area_a + areab - inter;
            float l = bn * den, r = inter * bd;
            // candidates enumerated in increasing p within the lane: strict > keeps first
            if (r > l) { bn = inter; bd = den; bp = (unsigned)p; }
        }
    }
    // cross-lane reduce of (bn,bd,bp): larger ratio wins; exact tie -> smaller p
#pragma unroll
    for (int s = 32; s > 0; s >>= 1) {
        float no = __shfl_xor(bn, s, 64), dd = __shfl_xor(bd, s, 64);
        unsigned po = __shfl_xor(bp, s, 64);
        float l = bn * dd, r = no * bd;
        bool take = (r > l) || (r == l && po < bp);
        if (take) { bn = no; bd = dd; bp = po; }
    }
    if (threadIdx.x == 0) {
        float iou = bn / bd;
        bp_final[b * O + o] = ((unsigned long long)__float_as_uint(iou) << 32)
                            | (unsigned)(0xFFFFFFFFu - bp);
    }
}

// ---------------- Kernel D1 (fused kA+kD, no-override epilogue, active-truth list):
// block bbox prunes the truth set ONCE per block; rational argmax (no per-pair divide).
__global__ void __launch_bounds__(256) kD1_main(
        const float* __restrict__ loc_data, const float* __restrict__ conf_data,
        const float* __restrict__ landm_data, const float* __restrict__ priors,
        const float* __restrict__ targets,
        float* __restrict__ rank, int* __restrict__ hist,
        int* __restrict__ num_pos, float* __restrict__ pos_ce,
        float* __restrict__ gsum, int* __restrict__ np1_tot) {
    int blk = blockIdx.x % NB2;
    int b = blockIdx.x / NB2;
    int p0 = blk * CHB;
    __shared__ float4 t4[O];
    __shared__ float ta[O], lab[O];
    __shared__ float lm[O][10];
    __shared__ int lhist[HB];
    __shared__ float4 wbb[4];
    __shared__ int alist[O];
    __shared__ int s_cnt;
    __shared__ float wredf[3][4];
    __shared__ int wredi[2][4];
    int tid = threadIdx.x;
    if (tid < O) {
        const float* t = &targets[(b * O + tid) * 15];
        float a0 = t[0], a1 = t[1], a2 = t[2], a3 = t[3];
        t4[tid] = make_float4(a0, a1, a2, a3);
        ta[tid] = (a2 - a0) * (a3 - a1);
        lab[tid] = t[14];
    }
    for (int i = tid; i < O * 10; i += 256)
        lm[i / 10][i % 10] = targets[b * O * 15 + (i / 10) * 15 + 4 + (i % 10)];
    for (int i = tid; i < HB; i += 256) lhist[i] = 0;
    // MULT priors in registers + per-wave bbox
    float px1[MULT], py1[MULT], px2[MULT], py2[MULT], areab[MULT];
    float4 pr4[MULT];
    float bnum[MULT], bden[MULT]; int bi[MULT]; bool act[MULT];
    float bx1 = 1e30f, by1 = 1e30f, bx2 = -1e30f, by2 = -1e30f;
#pragma unroll
    for (int mi = 0; mi < MULT; ++mi) {
        int p = p0 + mi * 256 + tid;
        act[mi] = (p < P);
        int pc = act[mi] ? p : (P - 1);
        float4 q = ((const float4*)priors)[pc];
        pr4[mi] = q;
        px1[mi] = q.x - q.z * 0.5f; py1[mi] = q.y - q.w * 0.5f;
        px2[mi] = q.x + q.z * 0.5f; py2[mi] = q.y + q.w * 0.5f;
        areab[mi] = (px2[mi] - px1[mi]) * (py2[mi] - py1[mi]);
        bx1 = fminf(bx1, px1[mi]); by1 = fminf(by1, py1[mi]);
        bx2 = fmaxf(bx2, px2[mi]); by2 = fmaxf(by2, py2[mi]);
        bnum[mi] = 0.f; bden[mi] = 1.f; bi[mi] = 0;   // iou 0, idx 0 (matches ref)
    }
    bx1 = wave_min(bx1); by1 = wave_min(by1);
    bx2 = wave_max(bx2); by2 = wave_max(by2);
    int wid = tid >> 6, lid = tid & 63;
    if (lid == 0) wbb[wid] = make_float4(bx1, by1, bx2, by2);
    __syncthreads();
    if (tid < 64) {
        float ux1 = fminf(fminf(wbb[0].x, wbb[1].x), fminf(wbb[2].x, wbb[3].x));
        float uy1 = fminf(fminf(wbb[0].y, wbb[1].y), fminf(wbb[2].y, wbb[3].y));
        float ux2 = fmaxf(fmaxf(wbb[0].z, wbb[1].z), fmaxf(wbb[2].z, wbb[3].z));
        float uy2 = fmaxf(fmaxf(wbb[0].w, wbb[1].w), fmaxf(wbb[2].w, wbb[3].w));
        float4 t = t4[tid];
        bool pass = (fminf(t.z, ux2) - fmaxf(t.x, ux1) > 0.f) &&
                    (fminf(t.w, uy2) - fmaxf(t.y, uy1) > 0.f);
        unsigned long long mask = __ballot(pass);
        if (tid == 0) s_cnt = __popcll(mask);
        if (pass) {
            int pos = __popcll(mask & ((1ull << tid) - 1ull));
            alist[pos] = tid;          // ballot-compaction preserves increasing o
        }
    }
    __syncthreads();
    int cnt = s_cnt;
    for (int li = 0; li < cnt; ++li) {
        int o = alist[li];
        float4 t = t4[o];
        float w0 = fminf(t.z, bx2) - fmaxf(t.x, bx1);
        float h0 = fminf(t.w, by2) - fmaxf(t.y, by1);
        if (w0 <= 0.f || h0 <= 0.f) continue;   // wave-uniform refinement (iou==0 skip)
        float area_a = ta[o];
#pragma unroll
        for (int mi = 0; mi < MULT; ++mi)
            iou_upd(t, area_a, px1[mi], py1[mi], px2[mi], py2[mi], areab[mi],
                    bnum[mi], bden[mi], bi[mi], o);
    }
    // per-prior epilogue (one division per prior; kC2 fixes the <=64 scattered priors)
    float ll = 0.f, llm = 0.f, cep = 0.f;
    int cp = 0, cp1 = 0;
#pragma unroll
    for (int mi = 0; mi < MULT; ++mi) {
        if (!act[mi]) continue;
        int p = p0 + mi * 256 + tid;
        float best = bnum[mi] / bden[mi];
        int conf = (best >= THRESH) ? (int)lab[bi[mi]] : 0;   // label +-1.0 exact
        float2 c01 = ((const float2*)conf_data)[b * P + p];
        float c0 = c01.x, c1 = c01.y;
        float lse = lse2(c0, c1);
        bool pos = conf != 0;
        float ce = lse - (pos ? c1 : c0);
        float rv = pos ? 0.f : ce;
        rank[(size_t)b * P + p] = rv;
        atomicAdd(&lhist[__float_as_uint(rv) >> HSHIFT], 1);
        if (pos) {
            cp++; cep += ce;
            int ti = bi[mi];
            float cx = pr4[mi].x, cy = pr4[mi].y, sw = pr4[mi].z, sh = pr4[mi].w;
            float4 t = t4[ti];
            float gx = ((t.x + t.z) * 0.5f - cx) / (0.1f * sw);
            float gy = ((t.y + t.w) * 0.5f - cy) / (0.1f * sh);
            float gw = logf((t.z - t.x) / sw) / 0.2f;
            float gh = logf((t.w - t.y) / sh) / 0.2f;
            const float* ld = &loc_data[(size_t)(b * P + p) * 4];
            ll += smooth_l1(ld[0] - gx) + smooth_l1(ld[1] - gy) +
                  smooth_l1(ld[2] - gw) + smooth_l1(ld[3] - gh);
            if (conf > 0) {
                cp1++;
                const float* lmd = &landm_data[(size_t)(b * P + p) * 10];
                for (int k5 = 0; k5 < 5; ++k5) {
                    float lx = (lm[ti][k5 * 2 + 0] - cx) / (0.1f * sw);
                    float ly = (lm[ti][k5 * 2 + 1] - cy) / (0.1f * sh);
                    llm += smooth_l1(lmd[k5 * 2 + 0] - lx) + smooth_l1(lmd[k5 * 2 + 1] - ly);
                }
            }
        }
    }
    float s_ll = wave_sum(ll), s_llm = wave_sum(llm), s_cep = wave_sum(cep);
    int s_cp = wave_sum_i(cp), s_cp1 = wave_sum_i(cp1);
    if (lid == 0) {
        wredf[0][wid] = s_ll; wredf[1][wid] = s_llm; wredf[2][wid] = s_cep;
        wredi[0][wid] = s_cp; wredi[1][wid] = s_cp1;
    }
    __syncthreads();
    if (tid == 0) {
        float ll_t = wredf[0][0] + wredf[0][1] + wredf[0][2] + wredf[0][3];
        float llm_t = wredf[1][0] + wredf[1][1] + wredf[1][2] + wredf[1][3];
        float cep_t = wredf[2][0] + wredf[2][1] + wredf[2][2] + wredf[2][3];
        int cp_t = wredi[0][0] + wredi[0][1] + wredi[0][2] + wredi[0][3];
        int cp1_t = wredi[1][0] + wredi[1][1] + wredi[1][2] + wredi[1][3];
        if (ll_t != 0.f)  atomicAdd(&gsum[0], ll_t);
        if (llm_t != 0.f) atomicAdd(&gsum[1], llm_t);
        if (cep_t != 0.f) atomicAdd(&pos_ce[b], cep_t);
        if (cp_t)  atomicAdd(&num_pos[b], cp_t);
        if (cp1_t) atomicAdd(np1_tot, cp1_t);
    }
    int* gh = hist + (size_t)b * HB;
#pragma unroll
    for (int i = tid; i < HB; i += 256) {
        int c = lhist[i];
        if (c) atomicAdd(&gh[i], c);
    }
}

// ---------------- Kernel C2 (fixup + findbin): dedup scatter (last j wins), recompute
// the <=64 overridden priors with the IDENTICAL rational argmax, apply deltas; hist
// fixed in an LDS copy and the coarse bin selected here.
__global__ void __launch_bounds__(256) kC2_fixup(
        const float* __restrict__ priors, const float* __restrict__ targets,
        const float* __restrict__ loc_data, const float* __restrict__ conf_data,
        const float* __restrict__ landm_data,
        const unsigned long long* __restrict__ bp_final,
        float* __restrict__ rank, const int* __restrict__ hist,
        int* __restrict__ num_pos, float* __restrict__ pos_ce,
        float* __restrict__ gsum, int* __restrict__ np1_tot, int* __restrict__ np_tot,
        int* __restrict__ binArr, int* __restrict__ kkArr) {
    int b = blockIdx.x;
    int tid = threadIdx.x;
    __shared__ float4 t4[O];
    __shared__ float ta[O], lab[O];
    __shared__ int sp[O];
    __shared__ int lh[HB];
    __shared__ int chunkSum[256];
    __shared__ int s_np;
    for (int i = tid; i < HB; i += 256) lh[i] = hist[(size_t)b * HB + i];
    int p = 0, v = 0;
    if (tid < O) {
        const float* tt = &targets[(b * O + tid) * 15];
        float4 tj = make_float4(tt[0], tt[1], tt[2], tt[3]);
        t4[tid] = tj;
        ta[tid] = (tj.z - tj.x) * (tj.w - tj.y);
        lab[tid] = tt[14];
        unsigned long long k = bp_final[b * O + tid];
        p = (int)(0xFFFFFFFFu - (unsigned)(k & 0xFFFFFFFFu));
        float iou = __uint_as_float((unsigned)(k >> 32));
        v = (iou >= VALID_T) ? 1 : 0;
        sp[tid] = p;
    }
    __syncthreads();
    int dnp = 0, dn1 = 0;
    float dll = 0.f, dllm = 0.f, dce = 0.f;
    if (tid < O) {
        int j = tid;
        bool winner = true;                // last j with this p wins (numpy scatter)
        for (int jj = j + 1; jj < O; ++jj)
            if (sp[jj] == p) { winner = false; break; }
        if (winner) {
            float4 q = ((const float4*)priors)[p];
            float px1 = q.x - q.z * 0.5f, py1 = q.y - q.w * 0.5f;
            float px2 = q.x + q.z * 0.5f, py2 = q.y + q.w * 0.5f;
            float areab = (px2 - px1) * (py2 - py1);
            float bnum = 0.f, bden = 1.f; int bi = 0;
            for (int o = 0; o < O; ++o)     // ascending o: bit-identical to hot path
                iou_upd(t4[o], ta[o], px1, py1, px2, py2, areab, bnum, bden, bi, o);
            float best = bnum / bden;
            float ov_new = v ? 2.0f : best;
            int conf_old = (best >= THRESH) ? (int)lab[bi] : 0;
            int conf_new = (ov_new >= THRESH) ? (int)lab[j] : 0;
            float2 c01 = ((const float2*)conf_data)[b * P + p];
            float c0 = c01.x, c1 = c01.y;
            float lse = lse2(c0, c1);
            bool po = conf_old != 0, pn = conf_new != 0;
            float ceo = lse - (po ? c1 : c0), cen = lse - (pn ? c1 : c0);
            float rvo = po ? 0.f : ceo, rvn = pn ? 0.f : cen;
            if (__float_as_uint(rvo) != __float_as_uint(rvn)) {
                rank[(size_t)b * P + p] = rvn;
                int bo = __float_as_uint(rvo) >> HSHIFT, bn = __float_as_uint(rvn) >> HSHIFT;
                if (bo != bn) { atomicAdd(&lh[bn], 1); atomicAdd(&lh[bo], -1); }
            }
            const float* ld = &loc_data[(size_t)(b * P + p) * 4];
            auto enc_ll = [&](int ti) -> float {    // same float ops as kD1 epilogue
                float4 t = t4[ti];
                float gx = ((t.x + t.z) * 0.5f - q.x) / (0.1f * q.z);
                float gy = ((t.y + t.w) * 0.5f - q.y) / (0.1f * q.w);
                float gw = logf((t.z - t.x) / q.z) / 0.2f;
                float gh = logf((t.w - t.y) / q.w) / 0.2f;
                return smooth_l1(ld[0] - gx) + smooth_l1(ld[1] - gy) +
                       smooth_l1(ld[2] - gw) + smooth_l1(ld[3] - gh);
            };
            if (po) dll -= enc_ll(bi);
            if (pn) dll += enc_ll(j);
            dce = (pn ? cen : 0.f) - (po ? ceo : 0.f);
            dnp = (int)pn - (int)po;
            const float* lmd = &landm_data[(size_t)(b * P + p) * 10];
            auto enc_lm = [&](int ti) -> float {
                const float* lmt = &targets[(b * O + ti) * 15 + 4];
                float sum = 0.f;
                for (int k5 = 0; k5 < 5; ++k5) {
                    float lx = (lmt[k5 * 2 + 0] - q.x) / (0.1f * q.z);
                    float ly = (lmt[k5 * 2 + 1] - q.y) / (0.1f * q.w);
                    sum += smooth_l1(lmd[k5 * 2 + 0] - lx) + smooth_l1(lmd[k5 * 2 + 1] - ly);
                }
                return sum;
            };
            if (conf_old > 0) dllm -= enc_lm(bi);
            if (conf_new > 0) dllm += enc_lm(j);
            dn1 = (int)(conf_new > 0) - (int)(conf_old > 0);
        }
    }
    if (tid < 64) {                        // wave 0 reduces the deltas
        float r_ll = wave_sum(dll), r_lm = wave_sum(dllm), r_ce = wave_sum(dce);
        int r_np = wave_sum_i(dnp), r_n1 = wave_sum_i(dn1);
        if (tid == 0) {
            if (r_ll != 0.f) atomicAdd(&gsum[0], r_ll);
            if (r_lm != 0.f) atomicAdd(&gsum[1], r_lm);
            if (r_ce != 0.f) pos_ce[b] += r_ce;        // row-private now
            int np = num_pos[b] + r_np;
            num_pos[b] = np;
            s_np = np;
            atomicAdd(np_tot, np);
            if (r_n1) atomicAdd(np1_tot, r_n1);
        }
    }
    __syncthreads();
    // ---- findbin (kE0 merged): hist is final in lh
    int k = s_np * 7;
    if (k > P - 1) k = P - 1;
    int cs = 0;
#pragma unroll
    for (int i = 0; i < HB / 256; ++i) cs += lh[tid * (HB / 256) + i];
    chunkSum[tid] = cs;
    __syncthreads();
    if (tid == 0) {
        if (k <= 0) { binArr[b] = -1; kkArr[b] = 0; return; }
        int cum = 0, bin = 0, kk = k;
        for (int c = 255; c >= 0; --c) {
            if (cum + chunkSum[c] >= k) {
                for (int i = HB / 256 - 1; i >= 0; --i) {
                    int hv = lh[c * (HB / 256) + i];
                    if (cum + hv >= k) { bin = c * (HB / 256) + i; kk = k - cum; goto found; }
                    cum += hv;
                }
            }
            cum += chunkSum[c];
        }
    found:
        binArr[b] = bin; kkArr[b] = kk;
    }
}

// ---------------- Kernel E1: parallel row scan — partial above-bin sum + candidate gather.
__global__ void kE1_scan(const float* __restrict__ rank, const int* __restrict__ binArr,
                         float* __restrict__ sumgt_part, unsigned* __restrict__ cand,
                         int* __restrict__ cand_cnt) {
    int seg = blockIdx.x % ESPLIT;
    int b = blockIdx.x / ESPLIT;
    int bin = binArr[b];
    if (bin < 0) return;
    const float* r = rank + (size_t)b * P;
    unsigned lo_bound = ((unsigned)(bin + 1)) << HSHIFT;
    __shared__ unsigned lc[PSEG];
    __shared__ int lcnt, gbase;
    __shared__ float wred[4];
    int t = threadIdx.x;
    if (t == 0) lcnt = 0;
    __syncthreads();
    int pend = min((seg + 1) * PSEG, P);
    float sumgt = 0.f;
    for (int p = seg * PSEG + t; p < pend; p += 256) {
        float v = r[p];
        unsigned u = __float_as_uint(v);
        if (u >= lo_bound) sumgt += v;
        else if ((u >> HSHIFT) == (unsigned)bin) {
            int idx = atomicAdd(&lcnt, 1);
            lc[idx] = u;
        }
    }
    __syncthreads();
    if (t == 0 && lcnt > 0) gbase = atomicAdd(&cand_cnt[b], lcnt);
    int wid = t >> 6, lid = t & 63;
    float s = wave_sum(sumgt);
    if (lid == 0) wred[wid] = s;
    __syncthreads();
    int n = lcnt, g0 = (n > 0) ? gbase : 0;
    for (int i = t; i < n; i += 256) {
        int d = g0 + i;
        if (d < CCAP) cand[(size_t)b * CCAP + d] = lc[i];
    }
    if (t == 0) {
        float tot = wred[0] + wred[1] + wred[2] + wred[3];
        if (tot != 0.f) atomicAdd(&sumgt_part[b], tot);
    }
}

// ---------------- Kernel E2: resolve remaining bits + final sum; LAST block writes out.
__global__ void kE2_resolve(const float* __restrict__ rank, const unsigned* __restrict__ cand,
                            const int* __restrict__ cand_cnt, const int* __restrict__ binArr,
                            const int* __restrict__ kkArr, const float* __restrict__ sumgt_part,
                            const float* __restrict__ pos_ce, float* __restrict__ gsum,
                            int* __restrict__ np_tot, int* __restrict__ np1_tot,
                            float* __restrict__ lossc_tot, int* __restrict__ done,
                            float* __restrict__ out) {
    int b = blockIdx.x;
    int bin = binArr[b];
    int t = threadIdx.x;
    __shared__ unsigned lcand[CCAP];
    __shared__ int hist2[256];
    __shared__ int s_bin, s_kk;
    __shared__ float redf[256];
    __shared__ int redi[256];
    float topk_b = 0.f;
    if (bin >= 0) {                      // block-uniform branch: __syncthreads safe
        int m = cand_cnt[b];
        int kk0 = kkArr[b];
        const unsigned* cd = cand + (size_t)b * CCAP;
        const float* r = rank + (size_t)b * P;
        bool useG = (m > CCAP);          // pathological overflow: rescan row
        if (!useG)
            for (int i = t; i < m; i += 256) lcand[i] = cd[i];
        __syncthreads();
        unsigned pref = ((unsigned)bin) << HSHIFT;
        unsigned resolved = 0xFFFFFFFFu << HSHIFT;
        int kk = kk0;
        const int shifts[3] = {13, 5, 0};
        const int nbins[3] = {256, 256, 32};
        for (int pass = 0; pass < 3; ++pass) {
            int sh = shifts[pass], nb = nbins[pass];
            for (int i = t; i < nb; i += 256) hist2[i] = 0;
            __syncthreads();
            if (!useG) {
                for (int i = t; i < m; i += 256) {
                    unsigned u = lcand[i];
                    if ((u & resolved) == pref) atomicAdd(&hist2[(u >> sh) & (nb - 1)], 1);
                }
            } else {
                for (int p = t; p < P; p += 256) {
                    unsigned u = __float_as_uint(r[p]);
                    if ((u & resolved) == pref) atomicAdd(&hist2[(u >> sh) & (nb - 1)], 1);
                }
            }
            __syncthreads();
            if (t == 0) {
                int cum = 0, d = 0, kn = kk;
                for (int i = nb - 1; i >= 0; --i) {
                    if (cum + hist2[i] >= kk) { d = i; kn = kk - cum; break; }
                    cum += hist2[i];
                }
                s_bin = d; s_kk = kn;
            }
            __syncthreads();
            pref |= ((unsigned)s_bin) << sh;
            resolved |= (unsigned)(nb - 1) << sh;
            kk = s_kk;
            __syncthreads();
        }
        float tv = __uint_as_float(pref);    // exact k-th largest value
        float sumS = 0.f; int cntS = 0;
        if (!useG) {
            for (int i = t; i < m; i += 256) {
                float v = __uint_as_float(lcand[i]);
                if (v > tv) { sumS += v; cntS++; }
            }
        } else {
            for (int p = t; p < P; p += 256) {
                unsigned u = __float_as_uint(r[p]);
                if ((u >> HSHIFT) == (unsigned)bin) {
                    float v = __uint_as_float(u);
                    if (v > tv) { sumS += v; cntS++; }
                }
            }
        }
        redf[t] = sumS; redi[t] = cntS; __syncthreads();
        for (int s = 128; s > 0; s >>= 1) {
            if (t < s) { redf[t] += redf[t + s]; redi[t] += redi[t + s]; }
            __syncthreads();
        }
        if (t == 0) topk_b = sumgt_part[b] + redf[0] + (float)(kk0 - redi[0]) * tv;
    }
    if (t == 0) {
        atomicAdd(lossc_tot, pos_ce[b] + topk_b);
        __threadfence();
        int old = atomicAdd(done, 1);
        if (old == B - 1) {              // last block finalizes (atomic reads: L2-fresh)
            float g0 = atomicAdd(&gsum[0], 0.f);
            float g1 = atomicAdd(&gsum[1], 0.f);
            float lc = atomicAdd(lossc_tot, 0.f);
            int np = atomicAdd(np_tot, 0);
            int n1 = atomicAdd(np1_tot, 0);
            float N = fmaxf((float)np, 1.f);
            float N1 = fmaxf((float)n1, 1.f);
            out[0] = g0 / N;
            out[1] = lc / N;
            out[2] = g1 / N1;
        }
    }
}

extern "C" void kernel_launch(void* const* d_in, const int* in_sizes, int n_in,
                              void* d_out, int out_size, void* d_ws, size_t ws_size,
                              hipStream_t stream) {
    const float* loc_data   = (const float*)d_in[0];
    const float* conf_data  = (const float*)d_in[1];
    const float* landm_data = (const float*)d_in[2];
    const float* priors     = (const float*)d_in[3];
    const float* targets    = (const float*)d_in[4];
    float* out = (float*)d_out;

    char* ws = (char*)d_ws;
    size_t off = 0;
    auto alloc = [&](size_t bytes) -> void* {
        void* p = ws + off;
        off += (bytes + 255) & ~(size_t)255;
        return p;
    };
    float* rank     = (float*)alloc((size_t)B * P * 4);
    unsigned long long* bp_final = (unsigned long long*)alloc((size_t)B * O * 8);
    unsigned* cand  = (unsigned*)alloc((size_t)B * CCAP * 4);
    int* binArr     = (int*)alloc(B * 4);
    int* kkArr      = (int*)alloc(B * 4);
    // zero region: hist (B*HB ints) + accumulators, contiguous
    size_t hist_bytes = (size_t)B * HB * 4;
    char* zbase = (char*)alloc(hist_bytes);
    int* hist = (int*)zbase;
    size_t acc_bytes = (size_t)(B * 4 * 4 + 64);
    char* acc = (char*)alloc(acc_bytes);
    int*   num_pos      = (int*)acc;
    float* pos_ce       = (float*)(acc + B * 4);
    int*   cand_cnt     = (int*)(acc + 2 * B * 4);
    float* sumgt_part   = (float*)(acc + 3 * B * 4);
    float* gsum         = (float*)(acc + 4 * B * 4);       // 2 floats
    int*   np1_tot      = (int*)(acc + 4 * B * 4 + 8);
    int*   np_tot       = (int*)(acc + 4 * B * 4 + 12);
    float* lossc_tot    = (float*)(acc + 4 * B * 4 + 16);
    int*   done         = (int*)(acc + 4 * B * 4 + 20);
    int ztot = (int)((hist_bytes + acc_bytes) / 4);

    kB2z<<<dim3(B * O), dim3(64), 0, stream>>>(priors, targets, bp_final, (int*)zbase, ztot);
    kD1_main<<<dim3(B * NB2), dim3(256), 0, stream>>>(loc_data, conf_data, landm_data, priors,
                                                      targets, rank, hist, num_pos, pos_ce,
                                                      gsum, np1_tot);
    kC2_fixup<<<dim3(B), dim3(256), 0, stream>>>(priors, targets, loc_data, conf_data,
                                                 landm_data, bp_final, rank, hist, num_pos,
                                                 pos_ce, gsum, np1_tot, np_tot, binArr, kkArr);
    kE1_scan<<<dim3(B * ESPLIT), dim3(256), 0, stream>>>(rank, binArr, sumgt_part, cand, cand_cnt);
    kE2_resolve<<<dim3(B), dim3(256), 0, stream>>>(rank, cand, cand_cnt, binArr, kkArr,
                                                   sumgt_part, pos_ce, gsum, np_tot, np1_tot,
                                                   lossc_tot, done, out);
}